// Round 3
// baseline (671.625 us; speedup 1.0000x reference)
//
#include <hip/hip_runtime.h>
#include <math.h>

#define B 64
#define S 2048
#define D 1024
#define H 300
#define NOUT 2
#define NCHUNK 16

typedef float fx4 __attribute__((ext_vector_type(4)));

static __device__ __forceinline__ int imin(int a, int b) { return a < b ? a : b; }

// ---------------------------------------------------------------------------
// Kernel 1: per-row end_ind + stable ballot compaction of surviving rows.
// One block per batch row. Emits cnt[b], srows[b][0..cnt), sw[b][0..cnt)
// (survivor s-indices in ascending order and their weights). ~5 us total.
// ---------------------------------------------------------------------------
__global__ __launch_bounds__(256) void compact_kernel(
        const int* __restrict__ ids,
        const float* __restrict__ drop,
        int* __restrict__ end_ind,
        int* __restrict__ cnt,
        unsigned short* __restrict__ srows /* [B][S] */,
        float* __restrict__ sw /* [B][S] */) {
    int b = blockIdx.x;
    int t = threadIdx.x;
    int lane = t & 63;
    int widx = t >> 6;

    // ---- end_ind: first s with ids[b,s]==1, fallback B ----
    const int* idrow = ids + (size_t)b * S;
    int m = S;
    for (int s = t; s < S; s += 256) {
        if (idrow[s] == 1 && s < m) m = s;
    }
    #pragma unroll
    for (int off = 32; off > 0; off >>= 1) m = imin(m, __shfl_xor(m, off, 64));
    __shared__ int wmin[4];
    if (lane == 0) wmin[widx] = m;
    __syncthreads();
    int e_full = imin(imin(wmin[0], wmin[1]), imin(wmin[2], wmin[3]));
    int e = (e_full < S) ? e_full : B;   // reference fallback: shape[0] == B
    if (t == 0) end_ind[b] = e;

    // ---- stable compaction: 32 segments of 64, wave w owns segs [8w, 8w+8) ----
    __shared__ int segcnt[32];
    __shared__ int segoff[33];
    const float* dr = drop + (size_t)b * S;

    float wv[8];
    int pos[8];
    bool pr[8];
    #pragma unroll
    for (int k = 0; k < 8; ++k) {
        int seg = widx * 8 + k;
        int s = seg * 64 + lane;
        float w = dr[s];
        bool p = (s < e) && (w != 0.f);
        unsigned long long mask = __ballot(p);
        wv[k] = w;
        pr[k] = p;
        pos[k] = __popcll(mask & ((1ull << lane) - 1ull));
        if (lane == 0) segcnt[seg] = __popcll(mask);
    }
    __syncthreads();
    if (t == 0) {
        int acc = 0;
        for (int i = 0; i < 32; ++i) { segoff[i] = acc; acc += segcnt[i]; }
        segoff[32] = acc;
        cnt[b] = acc;
    }
    __syncthreads();
    #pragma unroll
    for (int k = 0; k < 8; ++k) {
        if (pr[k]) {
            int seg = widx * 8 + k;
            int s = seg * 64 + lane;
            int o = segoff[seg] + pos[k];
            srows[(size_t)b * S + o] = (unsigned short)s;
            sw[(size_t)b * S + o] = wv[k];
        }
    }
}

// ---------------------------------------------------------------------------
// Kernel 2: balanced streaming partial sums. Block (b, j): survivor slice
// [j*cnt/16, (j+1)*cnt/16) of row b -> equal bytes per block within a row.
// Grid is b-fastest so a CU's co-resident blocks mix different rows
// (averages out cross-row count variance). Nontemporal fx4, 8-deep ILP.
// ---------------------------------------------------------------------------
__global__ __launch_bounds__(256) void sum_partial_kernel(
        const float* __restrict__ inputs,
        const int* __restrict__ cnt,
        const unsigned short* __restrict__ srows,
        const float* __restrict__ sw,
        float* __restrict__ partial /* [B][NCHUNK][D] */) {
    int b = blockIdx.x;   // fastest dim: consecutive blocks = different b
    int j = blockIdx.y;
    int t = threadIdx.x;

    int c = cnt[b];
    int lo = (j * c) >> 4;
    int hi = ((j + 1) * c) >> 4;
    int n = hi - lo;      // <= 128

    __shared__ unsigned short rows_l[128];
    __shared__ float w_l[128];
    if (t < n) {
        rows_l[t] = srows[(size_t)b * S + lo + t];
        w_l[t] = sw[(size_t)b * S + lo + t];
    }
    __syncthreads();

    fx4 a0 = (fx4)(0.f);
    fx4 a1 = a0, a2 = a0, a3 = a0, a4 = a0, a5 = a0, a6 = a0, a7 = a0;

    // thread t owns bytes [16t, 16t+16) of each 4KB row
    const char* base = (const char*)inputs
                     + ((size_t)b * S * D + 4 * (size_t)t) * sizeof(float);

    int i = 0;
    for (; i + 8 <= n; i += 8) {
        fx4 v0 = __builtin_nontemporal_load((const fx4*)(base + ((size_t)rows_l[i + 0] << 12)));
        fx4 v1 = __builtin_nontemporal_load((const fx4*)(base + ((size_t)rows_l[i + 1] << 12)));
        fx4 v2 = __builtin_nontemporal_load((const fx4*)(base + ((size_t)rows_l[i + 2] << 12)));
        fx4 v3 = __builtin_nontemporal_load((const fx4*)(base + ((size_t)rows_l[i + 3] << 12)));
        fx4 v4 = __builtin_nontemporal_load((const fx4*)(base + ((size_t)rows_l[i + 4] << 12)));
        fx4 v5 = __builtin_nontemporal_load((const fx4*)(base + ((size_t)rows_l[i + 5] << 12)));
        fx4 v6 = __builtin_nontemporal_load((const fx4*)(base + ((size_t)rows_l[i + 6] << 12)));
        fx4 v7 = __builtin_nontemporal_load((const fx4*)(base + ((size_t)rows_l[i + 7] << 12)));
        a0 += v0 * w_l[i + 0];
        a1 += v1 * w_l[i + 1];
        a2 += v2 * w_l[i + 2];
        a3 += v3 * w_l[i + 3];
        a4 += v4 * w_l[i + 4];
        a5 += v5 * w_l[i + 5];
        a6 += v6 * w_l[i + 6];
        a7 += v7 * w_l[i + 7];
    }
    for (; i < n; ++i) {
        fx4 v = __builtin_nontemporal_load((const fx4*)(base + ((size_t)rows_l[i] << 12)));
        a0 += v * w_l[i];
    }
    a0 = ((a0 + a1) + (a2 + a3)) + ((a4 + a5) + (a6 + a7));

    // Every block writes (zeros for empty slices) -> no memset needed.
    fx4* op = (fx4*)(partial + ((size_t)b * NCHUNK + j) * D) + t;
    *op = a0;
}

// ---------------------------------------------------------------------------
// Kernel 3: per-batch-row MLP, coalesced W1 access, 8 waves.
// ---------------------------------------------------------------------------
__global__ __launch_bounds__(512) void mlp_kernel(
        const float* __restrict__ partial,
        const int* __restrict__ end_ind,
        const float* __restrict__ W1, const float* __restrict__ b1,
        const float* __restrict__ W2, const float* __restrict__ b2,
        float* __restrict__ out) {
    int b = blockIdx.x;
    int t = threadIdx.x;
    int wave = t >> 6;
    int lane = t & 63;

    __shared__ fx4 x4[D / 4];        // 4 KB: euph row
    __shared__ float hidden[H];      // 1.2 KB
    __shared__ float red[512];

    float inv_e = 1.0f / (float)end_ind[b];
    if (t < D / 4) {
        fx4 a = (fx4)(0.f);
        const fx4* p = (const fx4*)(partial + (size_t)b * NCHUNK * D) + t;
        for (int c = 0; c < NCHUNK; ++c, p += D / 4) {
            a += p[0];
        }
        x4[t] = a * inv_e;
    }
    __syncthreads();

    fx4 xr0 = x4[lane];
    fx4 xr1 = x4[lane + 64];
    fx4 xr2 = x4[lane + 128];
    fx4 xr3 = x4[lane + 192];

    for (int h = wave; h < H; h += 8) {
        const fx4* w = (const fx4*)(W1 + (size_t)h * D);
        fx4 acc = xr0 * w[lane]
                + xr1 * w[lane + 64]
                + xr2 * w[lane + 128]
                + xr3 * w[lane + 192];
        float d = acc.x + acc.y + acc.z + acc.w;
        #pragma unroll
        for (int mm = 32; mm > 0; mm >>= 1) d += __shfl_xor(d, mm, 64);
        if (lane == 0) hidden[h] = tanhf(d + b1[h]);
    }
    __syncthreads();

    for (int o = 0; o < NOUT; ++o) {
        float p = 0.f;
        for (int h = t; h < H; h += 512) p += hidden[h] * W2[(size_t)o * H + h];
        red[t] = p;
        __syncthreads();
        for (int st = 256; st > 0; st >>= 1) {
            if (t < st) red[t] += red[t + st];
            __syncthreads();
        }
        if (t == 0) out[b * NOUT + o] = red[0] + b2[o];
        __syncthreads();
    }
}

// ---------------------------------------------------------------------------
extern "C" void kernel_launch(void* const* d_in, const int* in_sizes, int n_in,
                              void* d_out, int out_size, void* d_ws, size_t ws_size,
                              hipStream_t stream) {
    const float* inputs = (const float*)d_in[0];
    const int*   ids    = (const int*)d_in[1];
    const float* drop   = (const float*)d_in[2];
    const float* W1     = (const float*)d_in[3];
    const float* b1v    = (const float*)d_in[4];
    const float* W2     = (const float*)d_in[5];
    const float* b2v    = (const float*)d_in[6];
    float* out = (float*)d_out;

    // ws layout (all 4 KB-aligned):
    //   [0, 256):        end_ind (64 ints)
    //   [256, 512):      cnt     (64 ints)
    //   [4096, 266240):  srows   u16 [64][2048]  (256 KB)
    //   [266240, 790528): sw     f32 [64][2048]  (512 KB)
    //   [790528, ...):   partial f32 [64][16][1024] (4 MiB)
    int*            end_ind = (int*)d_ws;
    int*            cnt     = (int*)((char*)d_ws + 256);
    unsigned short* srows   = (unsigned short*)((char*)d_ws + 4096);
    float*          sw      = (float*)((char*)d_ws + 266240);
    float*          partial = (float*)((char*)d_ws + 790528);

    compact_kernel<<<B, 256, 0, stream>>>(ids, drop, end_ind, cnt, srows, sw);
    sum_partial_kernel<<<dim3(B, NCHUNK), 256, 0, stream>>>(inputs, cnt, srows, sw, partial);
    mlp_kernel<<<B, 512, 0, stream>>>(partial, end_ind, W1, b1v, W2, b2v, out);
}